// Round 6
// baseline (190.609 us; speedup 1.0000x reference)
//
#include <hip/hip_runtime.h>

#define ALPHA 0.9f
#define INV_ALPHA (1.0f / 0.9f)
#define EPS 1e-6f

constexpr int T_DIM  = 4096;
constexpr int B_DIM  = 16;
constexpr int D_DIM  = 1024;
constexpr int N_DIM  = 64;
constexpr int NPROJ  = 192;   // 3*n

constexpr int CHUNK_L = 64;   // outputs per chunk
constexpr int WARMUP  = 64;   // 0.9^64 ~ 1.2e-3
constexpr int NCHUNK  = T_DIM / CHUNK_L;   // 64
constexpr int GS      = 16;   // steps staged per LDS refill

typedef float  f32x4   __attribute__((ext_vector_type(4)));
typedef float  f32x2   __attribute__((ext_vector_type(2)));
typedef __bf16 bf16x8  __attribute__((ext_vector_type(8)));
typedef unsigned short ushort8 __attribute__((ext_vector_type(8)));
typedef _Float16 f16x8 __attribute__((ext_vector_type(8)));

__device__ __forceinline__ unsigned short f2bf(float f) {
  unsigned u = __builtin_bit_cast(unsigned, f);
  u += 0x7fffu + ((u >> 16) & 1u);          // RNE
  return (unsigned short)(u >> 16);
}
__device__ __forceinline__ float bf2f(unsigned short h) {
  unsigned u = ((unsigned)h) << 16;
  return __builtin_bit_cast(float, u);
}

// quad (4-lane) sum via DPP quad_perm — VALU pipe, no LDS traffic
__device__ __forceinline__ float quad_red(float v) {
  int x = __builtin_bit_cast(int, v);
  v += __builtin_bit_cast(float,
      __builtin_amdgcn_update_dpp(x, x, 0xB1, 0xF, 0xF, false));  // [1,0,3,2]
  x = __builtin_bit_cast(int, v);
  v += __builtin_bit_cast(float,
      __builtin_amdgcn_update_dpp(x, x, 0x4E, 0xF, 0xF, false));  // [2,3,0,1]
  return v;
}

// ---------------- W pre-conversion: fp32 -> bf16 hi/lo in frag-step layout ----------------
__global__ __launch_bounds__(256) void convert_w(
    const float* __restrict__ W, unsigned short* __restrict__ whi,
    unsigned short* __restrict__ wlo)
{
  int i = blockIdx.x * 256 + threadIdx.x;       // < 192*1024
  int c = i >> 10, k = i & 1023;
  float v = W[i];
  unsigned short h = f2bf(v);
  unsigned short l = f2bf(v - bf2f(h));
  int off = (k >> 5) * (NPROJ * 32) + c * 32 + (k & 31);
  whi[off] = h;
  wlo[off] = l;
}

// ---------------- MFMA projection GEMM: proj = x @ W^T (3-term split bf16) ----------------
constexpr int BM = 128, BK = 32, NS = D_DIM / BK;   // 32 K-steps

__global__ __launch_bounds__(512, 2) void proj_gemm(
    const float* __restrict__ x, const unsigned short* __restrict__ whi,
    const unsigned short* __restrict__ wlo, float* __restrict__ proj)
{
  __shared__ unsigned short As_hi[2][BM * BK];        // 16 KB
  __shared__ unsigned short As_lo[2][BM * BK];        // 16 KB
  __shared__ unsigned short Bs[2][2][NPROJ * BK];     // 48 KB

  const int tid  = threadIdx.x;
  const int w    = tid >> 6, lane = tid & 63;
  const int wr   = w >> 2, wc = w & 3;     // wave grid 2x4
  const int fr   = lane & 15, fg = lane >> 4;
  const int row0 = blockIdx.x * BM;

  const int arow = tid >> 2, akq = (tid & 3) * 8;
  const float* aSrc = x + (size_t)(row0 + arow) * D_DIM + akq;

  f32x4 acc[4][3];
#pragma unroll
  for (int i = 0; i < 4; ++i)
#pragma unroll
    for (int j = 0; j < 3; ++j) acc[i][j] = (f32x4){0.f, 0.f, 0.f, 0.f};

  float4 a0, a1;

  auto loadA = [&](int s) {
    const float* p = aSrc + s * BK;
    a0 = *(const float4*)p;
    a1 = *(const float4*)(p + 4);
  };
  auto writeA = [&](int buf) {
    float v[8] = {a0.x, a0.y, a0.z, a0.w, a1.x, a1.y, a1.z, a1.w};
    ushort8 h, l;
#pragma unroll
    for (int i = 0; i < 8; ++i) {
      __bf16 hb = (__bf16)v[i];            // native cvt (v_cvt_pk_bf16_f32 pairs)
      float  hf = (float)hb;
      __bf16 lb = (__bf16)(v[i] - hf);
      h[i] = __builtin_bit_cast(unsigned short, hb);
      l[i] = __builtin_bit_cast(unsigned short, lb);
    }
    *(ushort8*)&As_hi[buf][arow * BK + akq] = h;
    *(ushort8*)&As_lo[buf][arow * BK + akq] = l;
  };
  auto stageB = [&](int buf, int s) {
#pragma unroll
    for (int j = 0; j < 3; ++j) {
      const int f = (j * 8 + w) * 1024;
      const unsigned short* src;
      unsigned short* dst;
      if (f < 12288) {
        src = whi + (size_t)s * (NPROJ * 32) + (f >> 1);
        dst = &Bs[buf][0][f >> 1];
      } else {
        src = wlo + (size_t)s * (NPROJ * 32) + ((f - 12288) >> 1);
        dst = &Bs[buf][1][(f - 12288) >> 1];
      }
      __builtin_amdgcn_global_load_lds(
          (const __attribute__((address_space(1))) unsigned int*)(src) + lane * 4,
          (__attribute__((address_space(3))) unsigned int*)dst, 16, 0, 0);
    }
  };
  auto compute = [&](int buf) {
    bf16x8 ah[4], al[4];
#pragma unroll
    for (int ar = 0; ar < 4; ++ar) {
      const int off = (wr * 64 + ar * 16 + fr) * BK + fg * 8;
      ah[ar] = __builtin_bit_cast(bf16x8, *(const ushort8*)&As_hi[buf][off]);
      al[ar] = __builtin_bit_cast(bf16x8, *(const ushort8*)&As_lo[buf][off]);
    }
#pragma unroll
    for (int bc = 0; bc < 3; ++bc) {
      const int boff = (wc * 48 + bc * 16 + fr) * BK + fg * 8;
      bf16x8 bh = __builtin_bit_cast(bf16x8, *(const ushort8*)&Bs[buf][0][boff]);
      bf16x8 bl = __builtin_bit_cast(bf16x8, *(const ushort8*)&Bs[buf][1][boff]);
#pragma unroll
      for (int ar = 0; ar < 4; ++ar) {
        acc[ar][bc] = __builtin_amdgcn_mfma_f32_16x16x32_bf16(ah[ar], bh, acc[ar][bc], 0, 0, 0);
        acc[ar][bc] = __builtin_amdgcn_mfma_f32_16x16x32_bf16(ah[ar], bl, acc[ar][bc], 0, 0, 0);
        acc[ar][bc] = __builtin_amdgcn_mfma_f32_16x16x32_bf16(al[ar], bh, acc[ar][bc], 0, 0, 0);
      }
    }
  };

  loadA(0);
  stageB(0, 0);
  writeA(0);
  __syncthreads();

  int buf = 0;
  for (int s = 0; s < NS; ++s) {
    if (s + 1 < NS) {
      loadA(s + 1);
      stageB(buf ^ 1, s + 1);
    }
    compute(buf);
    if (s + 1 < NS) writeA(buf ^ 1);
    __syncthreads();
    buf ^= 1;
  }

#pragma unroll
  for (int ar = 0; ar < 4; ++ar) {
    const int row = row0 + wr * 64 + ar * 16 + fg * 4;
#pragma unroll
    for (int bc = 0; bc < 3; ++bc) {
      const int col = wc * 48 + bc * 16 + fr;
#pragma unroll
      for (int r = 0; r < 4; ++r)
        proj[(size_t)(row + r) * NPROJ + col] = acc[ar][bc][r];
    }
  }
}

// ---------------- prep: normalize k, emit compact f16 [kn|v|q] + fp32 kn.q ----------------
__global__ __launch_bounds__(256) void prep_kernel(
    const float* __restrict__ proj, _Float16* __restrict__ pf16,
    float* __restrict__ kqd)
{
  const int w = threadIdx.x >> 6, lane = threadIdx.x & 63;
  const int idx = blockIdx.x * 4 + w;               // t*B + b
  const float* p = proj + (size_t)idx * NPROJ;
  const float k = p[lane];
  const float v = p[64 + lane];
  const float q = p[128 + lane];
  float ss = k * k;
#pragma unroll
  for (int m = 1; m < 64; m <<= 1) ss += __shfl_xor(ss, m, 64);
  const float rn = 1.0f / (sqrtf(ss) + EPS);
  const float kn = k * rn;
  float kq = kn * q;
#pragma unroll
  for (int m = 1; m < 64; m <<= 1) kq += __shfl_xor(kq, m, 64);
  _Float16* o = pf16 + (size_t)idx * NPROJ;
  o[lane]       = (_Float16)kn;
  o[64 + lane]  = (_Float16)v;
  o[128 + lane] = (_Float16)q;
  if (lane == 0) kqd[idx] = kq;
}

// ---------------- scan: 4-wave, j-quartered S, f16 LDS staging, DPP reduces ----------------
__global__ __launch_bounds__(256) void scan_kernel(
    const _Float16* __restrict__ pf16, const float* __restrict__ kqd,
    const float* __restrict__ S0, float* __restrict__ out,
    float* __restrict__ Sfin)
{
  __shared__ __align__(16) char stage[2][GS * NPROJ * 2];   // 12 KB (f16 rows of 384B)
  __shared__ float stkq[2][GS];

  const int tid  = threadIdx.x;
  const int w    = tid >> 6, lane = tid & 63;
  const int qt   = lane & 3;                  // j-quarter
  const int r    = w * 16 + (lane >> 2);      // owned row
  const int b    = blockIdx.x & (B_DIM - 1);
  const int c    = blockIdx.x >> 4;

  const int t_out   = c * CHUNK_L;
  const int t_begin = (t_out >= WARMUP) ? (t_out - WARMUP) : 0;
  const int t_end   = t_out + CHUNK_L;
  const int ngroups = (t_end - t_begin) / GS;

  f32x2 s2[8];
  if (t_begin == 0) {
#pragma unroll
    for (int i = 0; i < 8; ++i)
      s2[i] = *(const f32x2*)&S0[((size_t)b * N_DIM + r) * N_DIM + qt * 16 + 2 * i];
  } else {
#pragma unroll
    for (int i = 0; i < 8; ++i) s2[i] = (f32x2){0.f, 0.f};
  }

  // group staging: 16 rows x 384B = 6 KB; 6 wave-slices of 1024B (linear LDS)
  auto issue = [&](int g, int pbuf) {
    const int t0 = t_begin + g * GS;
#pragma unroll
    for (int u = 0; u < 2; ++u) {
      const int sl = w + 4 * u;
      if (sl < 6) {
        const int gi = 64 * sl + lane;          // 16B-chunk index in [0,384)
        const int tl = gi / 24, cw = gi - tl * 24;
        const _Float16* src = pf16 + ((size_t)(t0 + tl) * B_DIM + b) * NPROJ + cw * 8;
        __builtin_amdgcn_global_load_lds(
            (const __attribute__((address_space(1))) unsigned int*)src,
            (__attribute__((address_space(3))) unsigned int*)(&stage[pbuf][0] + sl * 1024),
            16, 0, 0);
      }
    }
    if (tid < GS) {
      const float* src = kqd + (size_t)(t0 + tid) * B_DIM + b;
      __builtin_amdgcn_global_load_lds(
          (const __attribute__((address_space(1))) unsigned int*)src,
          (__attribute__((address_space(3))) unsigned int*)&stkq[pbuf][0],
          4, 0, 0);
    }
  };

  issue(0, 0);
  __syncthreads();

  float sc = 1.f, si = 1.f;

  for (int g = 0; g < ngroups; ++g) {
    const int p = g & 1;
    if (g + 1 < ngroups) issue(g + 1, p ^ 1);   // in flight under this group's compute

    const int tg = t_begin + g * GS;
    const bool op = (tg >= t_out);              // group-uniform

#pragma unroll
    for (int st = 0; st < GS; ++st) {
      const char* row = &stage[p][st * 384];
      // kn quarter: 16 f16 = 2 x b128
      const f16x8 ka = *(const f16x8*)(row + qt * 32);
      const f16x8 kb = *(const f16x8*)(row + qt * 32 + 16);
      const float vv = (float)*(const _Float16*)(row + 128 + 2 * r);
      const float kq = stkq[p][st];

      f32x2 kk[8];
#pragma unroll
      for (int i = 0; i < 4; ++i) {
        kk[i]     = (f32x2){(float)ka[2 * i], (float)ka[2 * i + 1]};
        kk[4 + i] = (f32x2){(float)kb[2 * i], (float)kb[2 * i + 1]};
      }

      f32x2 ra = s2[0] * kk[0];
      f32x2 rb = s2[1] * kk[1];
#pragma unroll
      for (int i = 2; i < 8; i += 2) {
        ra += s2[i] * kk[i];
        rb += s2[i + 1] * kk[i + 1];
      }
      const f32x2 rab = ra + rb;
      float rv = quad_red(rab.x + rab.y);

      float uv = 0.f;
      if (op) {
        const f16x8 qa = *(const f16x8*)(row + 256 + qt * 32);
        const f16x8 qb = *(const f16x8*)(row + 256 + qt * 32 + 16);
        f32x2 qq[8];
#pragma unroll
        for (int i = 0; i < 4; ++i) {
          qq[i]     = (f32x2){(float)qa[2 * i], (float)qa[2 * i + 1]};
          qq[4 + i] = (f32x2){(float)qb[2 * i], (float)qb[2 * i + 1]};
        }
        f32x2 ua = s2[0] * qq[0];
        f32x2 ub = s2[1] * qq[1];
#pragma unroll
        for (int i = 2; i < 8; i += 2) {
          ua += s2[i] * qq[i];
          ub += s2[i + 1] * qq[i + 1];
        }
        const f32x2 uab = ua + ub;
        uv = quad_red(uab.x + uab.y);
      }

      const float delta = vv - sc * rv;
      sc *= ALPHA; si *= INV_ALPHA;
      const float dinv = delta * si;
      const f32x2 d2 = (f32x2){dinv, dinv};

#pragma unroll
      for (int i = 0; i < 8; ++i) s2[i] += d2 * kk[i];

      if (op) {
        const float Sq  = sc * (uv + dinv * kq);
        const float sig = 1.0f / (1.0f + __expf(-Sq));
        if (qt == 0)
          out[((size_t)(tg + st) * B_DIM + b) * N_DIM + r] = Sq * Sq * sig;
      }
    }

    __syncthreads();   // drains vmcnt: next buffer complete; readers of p done
  }

  if (c == NCHUNK - 1) {
#pragma unroll
    for (int i = 0; i < 8; ++i) {
      Sfin[((size_t)b * N_DIM + r) * N_DIM + qt * 16 + 2 * i]     = sc * s2[i].x;
      Sfin[((size_t)b * N_DIM + r) * N_DIM + qt * 16 + 2 * i + 1] = sc * s2[i].y;
    }
  }
}

extern "C" void kernel_launch(void* const* d_in, const int* in_sizes, int n_in,
                              void* d_out, int out_size, void* d_ws, size_t ws_size,
                              hipStream_t stream)
{
  const float* x  = (const float*)d_in[0];
  const float* S0 = (const float*)d_in[1];
  const float* Wk = (const float*)d_in[2];
  float* out  = (float*)d_out;
  float* Sfin = out + (size_t)T_DIM * B_DIM * N_DIM;

  // ws layout (ws is ~1 GB):
  //   proj    @ 0          50,331,648 B (fp32 65536x192)
  //   whi     @ 50,331,648    393,216 B
  //   wlo     @ 50,724,864    393,216 B
  //   pf16    @ 51,118,080 25,165,824 B (f16 65536x192)
  //   kqd     @ 76,283,904    262,144 B
  char* wsb = (char*)d_ws;
  float*          proj = (float*)(wsb);
  unsigned short* whi  = (unsigned short*)(wsb + 50331648);
  unsigned short* wlo  = (unsigned short*)(wsb + 50724864);
  _Float16*       pf16 = (_Float16*)(wsb + 51118080);
  float*          kqd  = (float*)(wsb + 76283904);

  convert_w<<<(NPROJ * D_DIM) / 256, 256, 0, stream>>>(Wk, whi, wlo);
  proj_gemm<<<(T_DIM * B_DIM) / BM, 512, 0, stream>>>(x, whi, wlo, proj);
  prep_kernel<<<(T_DIM * B_DIM) / 4, 256, 0, stream>>>(proj, pf16, kqd);
  scan_kernel<<<B_DIM * NCHUNK, 256, 0, stream>>>(pf16, kqd, S0, out, Sfin);
}